// Round 1
// baseline (66.638 us; speedup 1.0000x reference)
//
#include <hip/hip_runtime.h>

// Problem constants (from reference setup_inputs)
#define B_   8
#define C_   3
#define O_   8
#define H_   128
#define W_   128
#define KS_  5
#define HO_  (H_ - KS_ + 1)   // 124
#define WO_  (W_ - KS_ + 1)   // 124
#define NPIX (HO_ * WO_)      // 15376
#define NTAP (KS_ * KS_)      // 25
#define BLK  256

// grid.y = b*C + c ; grid.x tiles the Ho*Wo pixel space
__global__ __launch_bounds__(BLK)
void mnn_kernel(const float* __restrict__ x,
                const float* __restrict__ Kh,
                const float* __restrict__ Km,
                float* __restrict__ out)
{
    __shared__ float sKh[O_ * NTAP];   // 200 floats
    __shared__ float sKm[O_ * NTAP];   // 200 floats

    const int bc = blockIdx.y;
    const int b  = bc / C_;
    const int c  = bc % C_;

    // Stage this channel's kernels: K[o][c][u][v] -> flat o*C*25 + c*25 + t
    for (int i = threadIdx.x; i < O_ * NTAP; i += BLK) {
        const int o = i / NTAP;
        const int t = i % NTAP;
        const int g = o * (C_ * NTAP) + c * NTAP + t;
        sKh[i] = Kh[g];
        sKm[i] = Km[g];
    }
    __syncthreads();

    const int p = blockIdx.x * BLK + threadIdx.x;
    if (p >= NPIX) return;
    const int ho = p / WO_;
    const int wo = p % WO_;

    // Load the 5x5 patch into registers (reused for all 8 o's x {hit,miss})
    float patch[NTAP];
    const float* xrow = x + ((b * C_ + c) * H_ + ho) * W_ + wo;
#pragma unroll
    for (int u = 0; u < KS_; ++u)
#pragma unroll
        for (int v = 0; v < KS_; ++v)
            patch[u * KS_ + v] = xrow[u * W_ + v];

    // out channel index = o*C + c ; flat: ((b*O*C + o*C + c)*HO + ho)*WO + wo
    const size_t obase = ((size_t)b * (O_ * C_) + c) * (size_t)NPIX + (size_t)ho * WO_ + wo;

#pragma unroll
    for (int o = 0; o < O_; ++o) {
        float hit  =  INFINITY;
        float miss = -INFINITY;
#pragma unroll
        for (int t = 0; t < NTAP; ++t) {
            hit  = fminf(hit,  patch[t] - sKh[o * NTAP + t]);
            miss = fmaxf(miss, patch[t] - sKm[o * NTAP + t]);
        }
        out[obase + (size_t)o * (C_ * NPIX)] = hit - miss;
    }
}

extern "C" void kernel_launch(void* const* d_in, const int* in_sizes, int n_in,
                              void* d_out, int out_size, void* d_ws, size_t ws_size,
                              hipStream_t stream)
{
    const float* x  = (const float*)d_in[0];
    const float* Kh = (const float*)d_in[1];
    const float* Km = (const float*)d_in[2];
    float* out = (float*)d_out;

    dim3 grid((NPIX + BLK - 1) / BLK, B_ * C_);
    dim3 block(BLK);
    mnn_kernel<<<grid, block, 0, stream>>>(x, Kh, Km, out);
}

// Round 3
// 65.752 us; speedup vs baseline: 1.0135x; 1.0135x over previous
//
#include <hip/hip_runtime.h>

// Problem constants (from reference setup_inputs)
#define B_    8
#define C_    3
#define O_    8
#define H_    128
#define W_    128
#define KS_   5
#define HO_   (H_ - KS_ + 1)   // 124
#define WO_   (W_ - KS_ + 1)   // 124
#define NPIX  (HO_ * WO_)      // 15376
#define NTAP  (KS_ * KS_)      // 25
#define PX    2                 // pixels per thread along wo
#define NG    (WO_ / PX)        // 62 groups per row
#define NPIXG (HO_ * NG)        // 7688 per (b,c)
#define BLK   256

// grid.y = b*C + c ; grid.x tiles the (ho, wo-group) space.
// K values are wave-uniform (c from blockIdx.y, o/t unrolled constants):
// the compiler emits s_load -> SGPRs, so the inner loop is pure VALU
// (v_sub_f32 v,v,s ; v_min_f32) with ZERO LDS traffic.
__global__ __launch_bounds__(BLK)
void mnn_kernel(const float* __restrict__ x,
                const float* __restrict__ Kh,
                const float* __restrict__ Km,
                float* __restrict__ out)
{
    const int bc = blockIdx.y;
    const int b  = bc / C_;
    const int c  = bc % C_;

    const int p = blockIdx.x * BLK + threadIdx.x;
    if (p >= NPIXG) return;
    const int ho  = p / NG;
    const int wo0 = (p % NG) * PX;

    // Load the 5x6 x-window into registers as float2s (cols wo0..wo0+5)
    float w[KS_][KS_ + PX - 1];
    const float* xrow = x + ((b * C_ + c) * H_ + ho) * W_ + wo0;
#pragma unroll
    for (int u = 0; u < KS_; ++u) {
#pragma unroll
        for (int v2 = 0; v2 < (KS_ + PX - 1 + 1) / 2; ++v2) {  // 3 float2 loads
            const float2 t = *reinterpret_cast<const float2*>(xrow + u * W_ + v2 * 2);
            w[u][v2 * 2 + 0] = t.x;
            w[u][v2 * 2 + 1] = t.y;
        }
    }

    // Uniform K bases for this channel: flat index o*(C*25) + c*25 + t
    const float* khc = Kh + c * NTAP;
    const float* kmc = Km + c * NTAP;

    const size_t obase = ((size_t)b * (O_ * C_) + c) * (size_t)NPIX
                       + (size_t)ho * WO_ + wo0;

#pragma unroll
    for (int o = 0; o < O_; ++o) {
        float hit0  =  INFINITY, hit1  =  INFINITY;
        float miss0 = -INFINITY, miss1 = -INFINITY;
#pragma unroll
        for (int u = 0; u < KS_; ++u) {
#pragma unroll
            for (int v = 0; v < KS_; ++v) {
                const int t = u * KS_ + v;
                const float kh = khc[o * (C_ * NTAP) + t];   // SGPR (uniform)
                const float km = kmc[o * (C_ * NTAP) + t];   // SGPR (uniform)
                hit0  = fminf(hit0,  w[u][v]     - kh);
                hit1  = fminf(hit1,  w[u][v + 1] - kh);
                miss0 = fmaxf(miss0, w[u][v]     - km);
                miss1 = fmaxf(miss1, w[u][v + 1] - km);
            }
        }
        float2 r;
        r.x = hit0 - miss0;
        r.y = hit1 - miss1;
        *reinterpret_cast<float2*>(out + obase + (size_t)o * (C_ * NPIX)) = r;
    }
}

extern "C" void kernel_launch(void* const* d_in, const int* in_sizes, int n_in,
                              void* d_out, int out_size, void* d_ws, size_t ws_size,
                              hipStream_t stream)
{
    const float* x  = (const float*)d_in[0];
    const float* Kh = (const float*)d_in[1];
    const float* Km = (const float*)d_in[2];
    float* out = (float*)d_out;

    dim3 grid((NPIXG + BLK - 1) / BLK, B_ * C_);
    dim3 block(BLK);
    mnn_kernel<<<grid, block, 0, stream>>>(x, Kh, Km, out);
}